// Round 7
// baseline (198.523 us; speedup 1.0000x reference)
//
#include <hip/hip_runtime.h>
#include <math.h>

// Problem constants
#define H 32
#define W 32
#define OH 94
#define OW 94
#define NMESH (OH * OW)   // 8836
#define B 4
#define M 4096
#define BM (B * M)        // 16384

// Mesh chunking: 256 chunks of 35 points, padded to 36.
#define NCHUNK 256
#define CH 35
#define CHPAD 36

// pc points per thread. P=8 + NCHUNK=256 gives grid 2048 blocks (8 waves/SIMD)
// AND 2x the arithmetic intensity per DS byte vs R6.
#define P 8

// DIAGNOSTIC AMPLIFICATION: repeat the full dist body R times (idempotent;
// bijective chunk permutation per pass prevents hoisting). dist's dur becomes
// R x true cost, lifting it above the ~41.5 us ws-poison fills so rocprof's
// top-5 finally shows ITS counters. Next round: R=1.
#define RREP 8

__global__ __launch_bounds__(256, 8) void dist_kernel(
        const float* __restrict__ nm, const float* __restrict__ pc,
        float* __restrict__ minpart, float* __restrict__ out) {
    int b = blockIdx.z;                            // 4
    int i0 = blockIdx.y * (256 * P) + threadIdx.x; // pc base point

    if (blockIdx.x == 0 && blockIdx.y == 0 && blockIdx.z == 0 && threadIdx.x == 0)
        out[0] = 0.0f;  // reduce_kernel (stream-ordered after us) accumulates

    __shared__ float4 sm[CHPAD];

    // pc loads: loop-invariant, issue once.
    float px[P], py[P], pz[P];
#pragma unroll
    for (int p = 0; p < P; ++p) {
        int i = i0 + p * 256;
        px[p] = pc[(b * 3 + 0) * M + i];
        py[p] = pc[(b * 3 + 1) * M + i];
        pz[p] = pc[(b * 3 + 2) * M + i];
    }

#pragma unroll 1
    for (int r = 0; r < RREP; ++r) {
        int chunk = (blockIdx.x + r * 37) & (NCHUNK - 1);  // bijection per pass

        // --- Stage: refine this chunk's 35 mesh points into LDS as
        // (-2x, -2y, -2z, ||m||^2); -2 premult (exact) -> pure 3-fma partial.
        if (threadIdx.x < CHPAD) {
            int k = threadIdx.x;
            int n = chunk * CH + k;
            if (k >= CH || n >= NMESH) {
                sm[k] = make_float4(0.f, 0.f, 0.f, 3.0e38f);  // sentinel
            } else {
                int oy = n / OW;
                int ox = n - oy * OW;
                float ys = (float)oy / 3.0f;
                float xs = (float)ox / 3.0f;
                int y0 = (int)floorf(ys); if (y0 > H - 2) y0 = H - 2;
                int x0 = (int)floorf(xs); if (x0 > W - 2) x0 = W - 2;
                float wy = ys - (float)y0;
                float wx = xs - (float)x0;
                const float* base = nm + b * 3 * H * W + y0 * W + x0;
                float vals[3];
#pragma unroll
                for (int c = 0; c < 3; ++c) {
                    const float* pp = base + c * H * W;
                    float v00 = pp[0], v01 = pp[1], v10 = pp[W], v11 = pp[W + 1];
                    float top = v00 * (1.0f - wx) + v01 * wx;
                    float bot = v10 * (1.0f - wx) + v11 * wx;
                    vals[c] = top * (1.0f - wy) + bot * wy;
                }
                float nrm = vals[0] * vals[0] + vals[1] * vals[1] + vals[2] * vals[2];
                sm[k] = make_float4(-2.f * vals[0], -2.f * vals[1], -2.f * vals[2], nrm);
            }
        }
        __syncthreads();

        float m[P];
#pragma unroll
        for (int p = 0; p < P; ++p) m[p] = 3.0e38f;

        for (int j = 0; j < CHPAD; j += 4) {
            float4 a0 = sm[j + 0];
            float4 a1 = sm[j + 1];
            float4 a2 = sm[j + 2];
            float4 a3 = sm[j + 3];
#pragma unroll
            for (int p = 0; p < P; ++p) {
                float s0 = fmaf(px[p], a0.x, fmaf(py[p], a0.y, fmaf(pz[p], a0.z, a0.w)));
                float s1 = fmaf(px[p], a1.x, fmaf(py[p], a1.y, fmaf(pz[p], a1.z, a1.w)));
                float s2 = fmaf(px[p], a2.x, fmaf(py[p], a2.y, fmaf(pz[p], a2.z, a2.w)));
                float s3 = fmaf(px[p], a3.x, fmaf(py[p], a3.y, fmaf(pz[p], a3.z, a3.w)));
                m[p] = fminf(fminf(fminf(m[p], s0), fminf(s1, s2)), s3);
            }
        }

#pragma unroll
        for (int p = 0; p < P; ++p)
            minpart[(chunk * B + b) * M + i0 + p * 256] = m[p];
        __syncthreads();  // protect sm against next pass's staging (WAR)
    }
}

// Kernel 2: fold 256 chunk-partials, add ||p||^2, mean via block reduce + atomicAdd.
__global__ __launch_bounds__(256) void reduce_kernel(
        const float* __restrict__ pc, const float* __restrict__ minpart,
        float* __restrict__ out) {
    int e = blockIdx.x * 256 + threadIdx.x;  // [0, 16384)
    int b = e >> 12;
    int i = e & (M - 1);

    float v = 3.0e38f;
#pragma unroll 8
    for (int c = 0; c < NCHUNK; ++c)
        v = fminf(v, minpart[(c * B + b) * M + i]);

    float px = pc[(b * 3 + 0) * M + i];
    float py = pc[(b * 3 + 1) * M + i];
    float pz = pc[(b * 3 + 2) * M + i];
    float pn = fmaf(px, px, fmaf(py, py, pz * pz));
    float d = v + pn;

    // wave64 reduce
    for (int off = 32; off > 0; off >>= 1)
        d += __shfl_down(d, off, 64);
    __shared__ float smem[4];
    int lane = threadIdx.x & 63;
    int wid = threadIdx.x >> 6;
    if (lane == 0) smem[wid] = d;
    __syncthreads();
    if (threadIdx.x == 0) {
        float s = (smem[0] + smem[1]) + (smem[2] + smem[3]);
        atomicAdd(out, s * (1.0f / (float)BM));
    }
}

extern "C" void kernel_launch(void* const* d_in, const int* in_sizes, int n_in,
                              void* d_out, int out_size, void* d_ws, size_t ws_size,
                              hipStream_t stream) {
    const float* nm = (const float*)d_in[0];   // (4,3,32,32)
    const float* pc = (const float*)d_in[1];   // (4,3,4096)
    float* out = (float*)d_out;                // scalar

    float* minpart = (float*)d_ws;             // 256*16384*4 = 16 MiB

    // grid: 256 chunks x 2 pc-tiles x 4 batches = 2048 blocks = 8 waves/SIMD
    dist_kernel<<<dim3(NCHUNK, M / (256 * P), B), 256, 0, stream>>>(nm, pc, minpart, out);

    reduce_kernel<<<BM / 256, 256, 0, stream>>>(pc, minpart, out);
}